// Round 12
// baseline (284.796 us; speedup 1.0000x reference)
//
#include <hip/hip_runtime.h>
#include <hip/hip_bf16.h>
#include <math.h>

typedef float f32x4 __attribute__((ext_vector_type(4)));
typedef float f32x4a __attribute__((ext_vector_type(4), aligned(4)));
typedef short s16x8 __attribute__((ext_vector_type(8)));
typedef short s16x16 __attribute__((ext_vector_type(16)));

#define B_  4
#define D_  512
#define L_  8192
#define CH_ 512
#define M_  1024   // interleaved (h,g) rows

__device__ __forceinline__ unsigned short f2bf(float f) {
    union { float f; unsigned u; } v; v.f = f;
    unsigned r = v.u + 0x7FFFu + ((v.u >> 16) & 1u);
    return (unsigned short)(r >> 16);
}

// ---------------------------------------------------------------------------
// Kernel 1: normalize h_w / g_w rows, interleave into Wn[1024][512] bf16.
// ---------------------------------------------------------------------------
__global__ __launch_bounds__(256)
void prep_kernel(const float* __restrict__ h_w, const float* __restrict__ g_w,
                 unsigned short* __restrict__ Wn) {
    __shared__ float red[4];
    const int ch = blockIdx.x, t = threadIdx.x;
    {
        float v0 = h_w[ch * 512 + t], v1 = h_w[ch * 512 + t + 256];
        float ss = v0 * v0 + v1 * v1;
        #pragma unroll
        for (int off = 32; off > 0; off >>= 1) ss += __shfl_down(ss, off, 64);
        if ((t & 63) == 0) red[t >> 6] = ss;
        __syncthreads();
        float tot = red[0] + red[1] + red[2] + red[3];
        float scale = 1.f / (sqrtf(tot) + 1e-4f * sqrtf(512.f));
        Wn[(size_t)(2 * ch) * 512 + t]       = f2bf(v0 * scale);
        Wn[(size_t)(2 * ch) * 512 + t + 256] = f2bf(v1 * scale);
    }
    __syncthreads();
    if (ch >= 2) {
        float v0 = g_w[(ch - 2) * 512 + t], v1 = g_w[(ch - 2) * 512 + t + 256];
        float ss = v0 * v0 + v1 * v1;
        #pragma unroll
        for (int off = 32; off > 0; off >>= 1) ss += __shfl_down(ss, off, 64);
        if ((t & 63) == 0) red[t >> 6] = ss;
        __syncthreads();
        float tot = red[0] + red[1] + red[2] + red[3];
        float scale = 1.f / (sqrtf(tot) + 1e-4f * sqrtf(512.f));
        Wn[(size_t)(2 * ch + 1) * 512 + t]       = f2bf(v0 * scale);
        Wn[(size_t)(2 * ch + 1) * 512 + t + 256] = f2bf(v1 * scale);
    } else {
        Wn[(size_t)(2 * ch + 1) * 512 + t]       = 0;
        Wn[(size_t)(2 * ch + 1) * 512 + t + 256] = 0;
    }
}

// ---------------------------------------------------------------------------
// Kernel 2: depthwise 5-tap conv, pad=2, bf16 out into C[b][d][l] (in d_out).
// ---------------------------------------------------------------------------
__global__ __launch_bounds__(256)
void conv_kernel(const float* __restrict__ x, const float* __restrict__ cw,
                 unsigned short* __restrict__ C) {
    __shared__ float xs[8200];
    const int row = blockIdx.x;          // b*512 + d
    const int d   = row & 511;
    const int t   = threadIdx.x;
    const float* xr = x + (size_t)row * L_;
    #pragma unroll
    for (int i = 0; i < 8; ++i) {
        float4 v = *(const float4*)&xr[(i * 256 + t) * 4];
        *(float4*)&xs[4 + (i * 256 + t) * 4] = v;
    }
    if (t < 4) xs[t] = 0.f;
    if (t >= 252) xs[8196 + (t - 252)] = 0.f;
    float w0 = cw[d * 5 + 0], w1 = cw[d * 5 + 1], w2 = cw[d * 5 + 2],
          w3 = cw[d * 5 + 3], w4 = cw[d * 5 + 4];
    float ss = w0 * w0 + w1 * w1 + w2 * w2 + w3 * w3 + w4 * w4;
    float scale = 1.f / (sqrtf(ss) + 1e-4f * sqrtf(5.f));
    w0 *= scale; w1 *= scale; w2 *= scale; w3 *= scale; w4 *= scale;
    __syncthreads();
    #pragma unroll
    for (int i = 0; i < 32; ++i) {
        int l = i * 256 + t;
        float acc = w0 * xs[l + 2] + w1 * xs[l + 3] + w2 * xs[l + 4]
                  + w3 * xs[l + 5] + w4 * xs[l + 6];
        C[(size_t)row * L_ + l] = f2bf(acc);
    }
}

// ---------------------------------------------------------------------------
// Kernel 2b: transpose C[b][512][8192] -> CT[(b*8192+l)][512] (bf16).
// ---------------------------------------------------------------------------
__global__ __launch_bounds__(256)
void transpose_kernel(const unsigned short* __restrict__ C,
                      unsigned short* __restrict__ CT) {
    __shared__ unsigned short tile[64 * 72];
    const int t  = threadIdx.x;
    const int l0 = blockIdx.x * 64, d0 = blockIdx.y * 64, b = blockIdx.z;
    {
        int r = t >> 2, seg = t & 3;
        s16x16 v = *(const s16x16*)&C[(size_t)(b * 512 + d0 + r) * L_ + l0 + seg * 16];
        *(s16x16*)&tile[r * 72 + seg * 16] = v;
    }
    __syncthreads();
    {
        int lr = t >> 2, seg = t & 3;
        unsigned short tmp[16];
        #pragma unroll
        for (int j = 0; j < 16; ++j) tmp[j] = tile[(seg * 16 + j) * 72 + lr];
        *(s16x16*)&CT[(size_t)(b * 8192 + l0 + lr) * 512 + d0 + seg * 16] =
            *(const s16x16*)tmp;
    }
}

// ---------------------------------------------------------------------------
// Kernel 3: bf16 MFMA GEMM, 128x128 tile, BK=32, 4 waves (64x64 each).
// Epilogue: hardware __expf/__logf -> (zb, la-with-sign) log-space outputs.
// ---------------------------------------------------------------------------
__global__ __launch_bounds__(256)
void gemm_kernel(const unsigned short* __restrict__ Wn,
                 const unsigned short* __restrict__ CT,
                 float* __restrict__ ZB, float* __restrict__ LA) {
    __shared__ unsigned short As[128 * 40];   // [row][k] stride 40 (2-way banks)
    __shared__ unsigned short Bs[128 * 40];
    const int t = threadIdx.x;
    const int lane = t & 63, w = t >> 6;
    const int wgid = ((blockIdx.x & 7) << 8) | (blockIdx.x >> 3);
    const int mBase = (wgid & 7) * 128;
    const int nBase = (wgid >> 3) * 128;

    const int srow = t >> 2, sq = t & 3;
    const int wrow = (w >> 1) * 64, wcol = (w & 1) * 64;

    f32x4 acc[4][4];
    #pragma unroll
    for (int fr = 0; fr < 4; ++fr)
        #pragma unroll
        for (int fc = 0; fc < 4; ++fc)
            acc[fr][fc] = (f32x4){0.f, 0.f, 0.f, 0.f};

    const unsigned short* aP0 = &Wn[(size_t)(mBase + srow) * 512 + sq * 8];
    const unsigned short* aP1 = &Wn[(size_t)(mBase + 64 + srow) * 512 + sq * 8];
    const unsigned short* bP0 = &CT[(size_t)(nBase + srow) * 512 + sq * 8];
    const unsigned short* bP1 = &CT[(size_t)(nBase + 64 + srow) * 512 + sq * 8];

    s16x8 a0v = *(const s16x8*)aP0;
    s16x8 a1v = *(const s16x8*)aP1;
    s16x8 b0v = *(const s16x8*)bP0;
    s16x8 b1v = *(const s16x8*)bP1;

    unsigned short* wA0 = &As[srow * 40 + sq * 8];
    unsigned short* wA1 = &As[(64 + srow) * 40 + sq * 8];
    unsigned short* wB0 = &Bs[srow * 40 + sq * 8];
    unsigned short* wB1 = &Bs[(64 + srow) * 40 + sq * 8];

    #pragma unroll
    for (int ks = 0; ks < 16; ++ks) {
        *(s16x8*)wA0 = a0v;
        *(s16x8*)wA1 = a1v;
        *(s16x8*)wB0 = b0v;
        *(s16x8*)wB1 = b1v;
        __syncthreads();
        if (ks < 15) {
            const int k0 = (ks + 1) * 32;
            a0v = *(const s16x8*)(aP0 + k0);
            a1v = *(const s16x8*)(aP1 + k0);
            b0v = *(const s16x8*)(bP0 + k0);
            b1v = *(const s16x8*)(bP1 + k0);
        }
        s16x8 af[4], bf[4];
        #pragma unroll
        for (int f = 0; f < 4; ++f) {
            af[f] = *(const s16x8*)&As[(wrow + f * 16 + (lane & 15)) * 40 + (lane >> 4) * 8];
            bf[f] = *(const s16x8*)&Bs[(wcol + f * 16 + (lane & 15)) * 40 + (lane >> 4) * 8];
        }
        #pragma unroll
        for (int fr = 0; fr < 4; ++fr)
            #pragma unroll
            for (int fc = 0; fc < 4; ++fc)
                acc[fr][fc] = __builtin_amdgcn_mfma_f32_16x16x32_bf16(
                    af[fr], bf[fc], acc[fr][fc], 0, 0, 0);
        __syncthreads();
    }

    #pragma unroll
    for (int fr = 0; fr < 4; ++fr)
    #pragma unroll
    for (int fc = 0; fc < 4; ++fc) {
        f32x4 a = acc[fr][fc];
        const int gR0 = mBase + wrow + fr * 16 + ((lane >> 4) * 4);
        const int n   = nBase + wcol + fc * 16 + (lane & 15);
        const int bb  = n >> 13, l = n & 8191;
        #pragma unroll
        for (int p = 0; p < 2; ++p) {
            float hv = a[2 * p], gv = a[2 * p + 1];
            const int ch = (gR0 >> 1) + p;
            if (ch == 0)      gv = -1000.f;
            else if (ch == 1) gv =  1000.f;
            float e  = __expf(-fabsf(gv));
            float l1 = __logf(1.f + e);                 // log1p(exp(-|g|))
            float la = fminf(-gv, 0.f) - l1;            // logsig(-g) <= 0
            float ls = fminf(gv, 0.f) - l1;             // logsig(g)
            float zb = ls + __logf(fmaxf(fabsf(hv), 1e-6f));
            float enc = (hv < 0.f) ? fabsf(la) : -fabsf(la);
            size_t off = ((size_t)bb * CH_ + ch) * L_ + l;
            ZB[off] = zb;
            LA[off] = enc;
        }
    }
}

// ---------------------------------------------------------------------------
// Kernel 3b: recompute h[b][1][:] in full f32, rewrite ch1's (la, zb).
// R11 FIX: asm keep-alives failed (compiler re-issued loads; VGPR stayed 52,
// FETCH rose).  Now: software pipeline with sched_barrier(0)-pinned phases,
// double-buffered groups of 8 rows, and vector loads (1 dwordx4 + 1 dword
// per row = same 5 values).  FMA tree and ascending-d order byte-identical.
// Edge threads (l<2 or l>L-3; 4 per batch) take the old scalar-select path.
// ---------------------------------------------------------------------------
__global__ __launch_bounds__(128)
void fixch1_kernel(const float* __restrict__ x, const float* __restrict__ cw,
                   const float* __restrict__ h_w,
                   float* __restrict__ ZB, float* __restrict__ LA) {
    __shared__ float wc[512][5];
    __shared__ float w1n[512];
    __shared__ float red[2];
    const int b = blockIdx.y;
    const int l = blockIdx.x * 128 + threadIdx.x;
    const int t = threadIdx.x;
    const int lane = t & 63, wid = t >> 6;
    for (int d = t; d < 512; d += 128) {
        float a0 = cw[d * 5 + 0], a1 = cw[d * 5 + 1], a2 = cw[d * 5 + 2],
              a3 = cw[d * 5 + 3], a4 = cw[d * 5 + 4];
        float ss = a0 * a0 + a1 * a1 + a2 * a2 + a3 * a3 + a4 * a4;
        float sc = 1.f / (sqrtf(ss) + 1e-4f * sqrtf(5.f));
        wc[d][0] = a0 * sc; wc[d][1] = a1 * sc; wc[d][2] = a2 * sc;
        wc[d][3] = a3 * sc; wc[d][4] = a4 * sc;
    }
    {
        float v0 = h_w[512 + t],       v1 = h_w[512 + t + 128];
        float v2 = h_w[512 + t + 256], v3 = h_w[512 + t + 384];
        float ss = v0 * v0 + v1 * v1 + v2 * v2 + v3 * v3;
        #pragma unroll
        for (int off = 32; off > 0; off >>= 1) ss += __shfl_down(ss, off, 64);
        if (lane == 0) red[wid] = ss;
        __syncthreads();
        float tot = red[0] + red[1];
        float sc = 1.f / (sqrtf(tot) + 1e-4f * sqrtf(512.f));
        w1n[t]       = v0 * sc;
        w1n[t + 128] = v1 * sc;
        w1n[t + 256] = v2 * sc;
        w1n[t + 384] = v3 * sc;
    }
    __syncthreads();
    const float* xb = x + (size_t)b * D_ * L_;
    float acc = 0.f;
    const bool interior = (l >= 2) && (l <= L_ - 3);
    if (interior) {
        const float* xp = xb + (l - 2);     // v4 = x[l-2..l+1], s = x[l+2]
        f32x4a vA[8], vB[8];
        float  sA[8], sB[8];
#define FX_LOAD(V, S, g) do { const int d0_ = (g) * 8;                        \
        _Pragma("unroll")                                                     \
        for (int u = 0; u < 8; ++u) {                                         \
            const float* xr_ = xp + (size_t)(d0_ + u) * L_;                   \
            V[u] = *(const f32x4a*)xr_;                                       \
            S[u] = xr_[4];                                                    \
        } } while (0)
#define FX_CONS(V, S, g) do { const int d0_ = (g) * 8;                        \
        _Pragma("unroll")                                                     \
        for (int u = 0; u < 8; ++u) {                                         \
            float cv_ = wc[d0_ + u][0] * V[u][0] + wc[d0_ + u][1] * V[u][1]   \
                      + wc[d0_ + u][2] * V[u][2] + wc[d0_ + u][3] * V[u][3]   \
                      + wc[d0_ + u][4] * S[u];                                \
            acc += w1n[d0_ + u] * cv_;                                        \
        } } while (0)
        FX_LOAD(vA, sA, 0);
        __builtin_amdgcn_sched_barrier(0);
        for (int g = 0; g < 62; g += 2) {
            FX_LOAD(vB, sB, g + 1);
            __builtin_amdgcn_sched_barrier(0);
            FX_CONS(vA, sA, g);
            __builtin_amdgcn_sched_barrier(0);
            FX_LOAD(vA, sA, g + 2);
            __builtin_amdgcn_sched_barrier(0);
            FX_CONS(vB, sB, g + 1);
            __builtin_amdgcn_sched_barrier(0);
        }
        FX_LOAD(vB, sB, 63);
        __builtin_amdgcn_sched_barrier(0);
        FX_CONS(vA, sA, 62);
        FX_CONS(vB, sB, 63);
#undef FX_LOAD
#undef FX_CONS
    } else {
        const bool lo2 = (l >= 2), lo1 = (l >= 1);
        const bool hi1 = (l + 1 < L_), hi2 = (l + 2 < L_);
        for (int d = 0; d < 512; ++d) {
            const float* xr = xb + (size_t)d * L_;
            float x0 = lo2 ? xr[l - 2] : 0.f;
            float x1 = lo1 ? xr[l - 1] : 0.f;
            float x2 = xr[l];
            float x3 = hi1 ? xr[l + 1] : 0.f;
            float x4 = hi2 ? xr[l + 2] : 0.f;
            float cv = wc[d][0] * x0 + wc[d][1] * x1 + wc[d][2] * x2
                     + wc[d][3] * x3 + wc[d][4] * x4;
            acc += w1n[d] * cv;
        }
    }
    size_t off = ((size_t)b * CH_ + 1) * L_ + l;
    LA[off] = (acc < 0.f) ? 1000.f : -1000.f;    // la=-1000, sign(h) packed
    ZB[off] = logf(fmaxf(fabsf(acc), 1e-6f));    // logsig(1000)=0
}

// ---------------------------------------------------------------------------
// Kernel 4: log-space scan from precomputed (la_enc, zb).
// ---------------------------------------------------------------------------
struct LV { float re, sg; };

__device__ __forceinline__ LV lcomb(LV a, LV b) {
    float m  = fmaxf(a.re, b.re);
    float ms = (m > -3.0e38f) ? m : 0.f;
    float s  = a.sg * __expf(a.re - ms) + b.sg * __expf(b.re - ms);
    LV r;
    r.re = ms + __logf(fabsf(s));
    r.sg = (s < 0.f) ? -1.f : 1.f;
    return r;
}

__global__ __launch_bounds__(256)
void logscan_kernel(const float* __restrict__ LA, float* __restrict__ ZO) {
    __shared__ float wA[4];
    __shared__ float wRe[4], wSg[4];
    const int row = blockIdx.x;
    const int t = threadIdx.x;
    const int lane = t & 63, wid = t >> 6;
    const float* ep = LA + (size_t)row * L_;
    float* zp = ZO + (size_t)row * L_;

    float As[32];
    unsigned sgb = 0;
    float run = 0.f;
    #pragma unroll
    for (int i = 0; i < 8; ++i) {
        float4 e4 = *(const float4*)&ep[t * 32 + i * 4];
        float ev0 = e4.x, ev1 = e4.y, ev2 = e4.z, ev3 = e4.w;
        if (!(__float_as_uint(ev0) >> 31)) sgb |= (1u << (i * 4 + 0));
        if (!(__float_as_uint(ev1) >> 31)) sgb |= (1u << (i * 4 + 1));
        if (!(__float_as_uint(ev2) >> 31)) sgb |= (1u << (i * 4 + 2));
        if (!(__float_as_uint(ev3) >> 31)) sgb |= (1u << (i * 4 + 3));
        run -= fabsf(ev0); As[i * 4 + 0] = run;
        run -= fabsf(ev1); As[i * 4 + 1] = run;
        run -= fabsf(ev2); As[i * 4 + 2] = run;
        run -= fabsf(ev3); As[i * 4 + 3] = run;
    }
    float wsc = run;
    #pragma unroll
    for (int off = 1; off < 64; off <<= 1) {
        float u = __shfl_up(wsc, off, 64);
        if (lane >= off) wsc += u;
    }
    if (lane == 63) wA[wid] = wsc;
    __syncthreads();
    float pre = wsc - run;
    for (int j = 0; j < wid; ++j) pre += wA[j];
    #pragma unroll
    for (int i = 0; i < 32; ++i) As[i] += pre;

    float zz[32];
    LV tot = { -INFINITY, 1.f };
    #pragma unroll
    for (int i = 0; i < 8; ++i) {
        float4 z4 = *(const float4*)&zp[t * 32 + i * 4];
        float zv0 = z4.x, zv1 = z4.y, zv2 = z4.z, zv3 = z4.w;
        #pragma unroll
        for (int j = 0; j < 4; ++j) {
            int k = i * 4 + j;
            float zvj = (j == 0) ? zv0 : (j == 1) ? zv1 : (j == 2) ? zv2 : zv3;
            zz[k] = zvj - As[k];
            LV zi = { zz[k], ((sgb >> k) & 1) ? -1.f : 1.f };
            tot = lcomb(tot, zi);
        }
    }
    LV sc = tot;
    #pragma unroll
    for (int off = 1; off < 64; off <<= 1) {
        float ure = __shfl_up(sc.re, off, 64);
        float usg = __shfl_up(sc.sg, off, 64);
        if (lane >= off) { LV u = { ure, usg }; sc = lcomb(u, sc); }
    }
    if (lane == 63) { wRe[wid] = sc.re; wSg[wid] = sc.sg; }
    __syncthreads();
    float pr = __shfl_up(sc.re, 1, 64);
    float ps = __shfl_up(sc.sg, 1, 64);
    LV lex = { -INFINITY, 1.f };
    if (lane != 0) { lex.re = pr; lex.sg = ps; }
    LV wpre = { -INFINITY, 1.f };
    for (int j = 0; j < wid; ++j) { LV u = { wRe[j], wSg[j] }; wpre = lcomb(wpre, u); }
    LV pref = lcomb(wpre, lex);

    LV run2 = pref;
    #pragma unroll
    for (int i = 0; i < 8; ++i) {
        float4 o4;
        #pragma unroll
        for (int j = 0; j < 4; ++j) {
            int k = i * 4 + j;
            LV zi = { zz[k], ((sgb >> k) & 1) ? -1.f : 1.f };
            run2 = lcomb(run2, zi);
            float ov = run2.sg * __expf(As[k] + run2.re);
            if (j == 0) o4.x = ov; else if (j == 1) o4.y = ov;
            else if (j == 2) o4.z = ov; else o4.w = ov;
        }
        *(float4*)&zp[t * 32 + i * 4] = o4;
    }
}

// ---------------------------------------------------------------------------
extern "C" void kernel_launch(void* const* d_in, const int* in_sizes, int n_in,
                              void* d_out, int out_size, void* d_ws, size_t ws_size,
                              hipStream_t stream) {
    const float* x      = (const float*)d_in[0];
    const float* conv_w = (const float*)d_in[1];
    const float* h_w    = (const float*)d_in[2];
    const float* g_w    = (const float*)d_in[3];
    float* out = (float*)d_out;
    char* ws = (char*)d_ws;

    // ws layout (97 MB): CT bf16 [32768][512] = 32MB | Wn bf16 1MB | LA f32 64MB
    unsigned short* CT  = (unsigned short*)ws;
    unsigned short* Wn  = (unsigned short*)(ws + (size_t)32 * 1024 * 1024);
    float*          la  = (float*)(ws + (size_t)33 * 1024 * 1024);
    unsigned short* C   = (unsigned short*)d_out;

    prep_kernel<<<512, 256, 0, stream>>>(h_w, g_w, Wn);
    conv_kernel<<<B_ * D_, 256, 0, stream>>>(x, conv_w, C);
    transpose_kernel<<<dim3(128, 8, 4), 256, 0, stream>>>(C, CT);
    gemm_kernel<<<2048, 256, 0, stream>>>(Wn, CT, out, la);
    fixch1_kernel<<<dim3(L_ / 128, B_), 128, 0, stream>>>(x, conv_w, h_w, out, la);
    logscan_kernel<<<B_ * CH_, 256, 0, stream>>>(la, out);
}

// Round 13
// 166.580 us; speedup vs baseline: 1.7097x; 1.7097x over previous
//
#include <hip/hip_runtime.h>
#include <hip/hip_bf16.h>
#include <math.h>

typedef float f32x4 __attribute__((ext_vector_type(4)));
typedef short s16x8 __attribute__((ext_vector_type(8)));
typedef short s16x16 __attribute__((ext_vector_type(16)));

#define B_  4
#define D_  512
#define L_  8192
#define CH_ 512
#define M_  1024   // interleaved (h,g) rows

__device__ __forceinline__ unsigned short f2bf(float f) {
    union { float f; unsigned u; } v; v.f = f;
    unsigned r = v.u + 0x7FFFu + ((v.u >> 16) & 1u);
    return (unsigned short)(r >> 16);
}

// ---------------------------------------------------------------------------
// Kernel 1: normalize h_w / g_w rows, interleave into Wn[1024][512] bf16.
// ---------------------------------------------------------------------------
__global__ __launch_bounds__(256)
void prep_kernel(const float* __restrict__ h_w, const float* __restrict__ g_w,
                 unsigned short* __restrict__ Wn) {
    __shared__ float red[4];
    const int ch = blockIdx.x, t = threadIdx.x;
    {
        float v0 = h_w[ch * 512 + t], v1 = h_w[ch * 512 + t + 256];
        float ss = v0 * v0 + v1 * v1;
        #pragma unroll
        for (int off = 32; off > 0; off >>= 1) ss += __shfl_down(ss, off, 64);
        if ((t & 63) == 0) red[t >> 6] = ss;
        __syncthreads();
        float tot = red[0] + red[1] + red[2] + red[3];
        float scale = 1.f / (sqrtf(tot) + 1e-4f * sqrtf(512.f));
        Wn[(size_t)(2 * ch) * 512 + t]       = f2bf(v0 * scale);
        Wn[(size_t)(2 * ch) * 512 + t + 256] = f2bf(v1 * scale);
    }
    __syncthreads();
    if (ch >= 2) {
        float v0 = g_w[(ch - 2) * 512 + t], v1 = g_w[(ch - 2) * 512 + t + 256];
        float ss = v0 * v0 + v1 * v1;
        #pragma unroll
        for (int off = 32; off > 0; off >>= 1) ss += __shfl_down(ss, off, 64);
        if ((t & 63) == 0) red[t >> 6] = ss;
        __syncthreads();
        float tot = red[0] + red[1] + red[2] + red[3];
        float scale = 1.f / (sqrtf(tot) + 1e-4f * sqrtf(512.f));
        Wn[(size_t)(2 * ch + 1) * 512 + t]       = f2bf(v0 * scale);
        Wn[(size_t)(2 * ch + 1) * 512 + t + 256] = f2bf(v1 * scale);
    } else {
        Wn[(size_t)(2 * ch + 1) * 512 + t]       = 0;
        Wn[(size_t)(2 * ch + 1) * 512 + t + 256] = 0;
    }
}

// ---------------------------------------------------------------------------
// Kernel 2: depthwise 5-tap conv, pad=2, bf16 out into C[b][d][l] (in d_out).
// ---------------------------------------------------------------------------
__global__ __launch_bounds__(256)
void conv_kernel(const float* __restrict__ x, const float* __restrict__ cw,
                 unsigned short* __restrict__ C) {
    __shared__ float xs[8200];
    const int row = blockIdx.x;          // b*512 + d
    const int d   = row & 511;
    const int t   = threadIdx.x;
    const float* xr = x + (size_t)row * L_;
    #pragma unroll
    for (int i = 0; i < 8; ++i) {
        float4 v = *(const float4*)&xr[(i * 256 + t) * 4];
        *(float4*)&xs[4 + (i * 256 + t) * 4] = v;
    }
    if (t < 4) xs[t] = 0.f;
    if (t >= 252) xs[8196 + (t - 252)] = 0.f;
    float w0 = cw[d * 5 + 0], w1 = cw[d * 5 + 1], w2 = cw[d * 5 + 2],
          w3 = cw[d * 5 + 3], w4 = cw[d * 5 + 4];
    float ss = w0 * w0 + w1 * w1 + w2 * w2 + w3 * w3 + w4 * w4;
    float scale = 1.f / (sqrtf(ss) + 1e-4f * sqrtf(5.f));
    w0 *= scale; w1 *= scale; w2 *= scale; w3 *= scale; w4 *= scale;
    __syncthreads();
    #pragma unroll
    for (int i = 0; i < 32; ++i) {
        int l = i * 256 + t;
        float acc = w0 * xs[l + 2] + w1 * xs[l + 3] + w2 * xs[l + 4]
                  + w3 * xs[l + 5] + w4 * xs[l + 6];
        C[(size_t)row * L_ + l] = f2bf(acc);
    }
}

// ---------------------------------------------------------------------------
// Kernel 2b: transpose C[b][512][8192] -> CT[(b*8192+l)][512] (bf16).
// ---------------------------------------------------------------------------
__global__ __launch_bounds__(256)
void transpose_kernel(const unsigned short* __restrict__ C,
                      unsigned short* __restrict__ CT) {
    __shared__ unsigned short tile[64 * 72];
    const int t  = threadIdx.x;
    const int l0 = blockIdx.x * 64, d0 = blockIdx.y * 64, b = blockIdx.z;
    {
        int r = t >> 2, seg = t & 3;
        s16x16 v = *(const s16x16*)&C[(size_t)(b * 512 + d0 + r) * L_ + l0 + seg * 16];
        *(s16x16*)&tile[r * 72 + seg * 16] = v;
    }
    __syncthreads();
    {
        int lr = t >> 2, seg = t & 3;
        unsigned short tmp[16];
        #pragma unroll
        for (int j = 0; j < 16; ++j) tmp[j] = tile[(seg * 16 + j) * 72 + lr];
        *(s16x16*)&CT[(size_t)(b * 8192 + l0 + lr) * 512 + d0 + seg * 16] =
            *(const s16x16*)tmp;
    }
}

// ---------------------------------------------------------------------------
// Kernel 3: bf16 MFMA GEMM, 128x128 tile, BK=32, 4 waves (64x64 each).
// Epilogue: hardware __expf/__logf -> (zb, la-with-sign) log-space outputs.
// ---------------------------------------------------------------------------
__global__ __launch_bounds__(256)
void gemm_kernel(const unsigned short* __restrict__ Wn,
                 const unsigned short* __restrict__ CT,
                 float* __restrict__ ZB, float* __restrict__ LA) {
    __shared__ unsigned short As[128 * 40];   // [row][k] stride 40 (2-way banks)
    __shared__ unsigned short Bs[128 * 40];
    const int t = threadIdx.x;
    const int lane = t & 63, w = t >> 6;
    const int wgid = ((blockIdx.x & 7) << 8) | (blockIdx.x >> 3);
    const int mBase = (wgid & 7) * 128;
    const int nBase = (wgid >> 3) * 128;

    const int srow = t >> 2, sq = t & 3;
    const int wrow = (w >> 1) * 64, wcol = (w & 1) * 64;

    f32x4 acc[4][4];
    #pragma unroll
    for (int fr = 0; fr < 4; ++fr)
        #pragma unroll
        for (int fc = 0; fc < 4; ++fc)
            acc[fr][fc] = (f32x4){0.f, 0.f, 0.f, 0.f};

    const unsigned short* aP0 = &Wn[(size_t)(mBase + srow) * 512 + sq * 8];
    const unsigned short* aP1 = &Wn[(size_t)(mBase + 64 + srow) * 512 + sq * 8];
    const unsigned short* bP0 = &CT[(size_t)(nBase + srow) * 512 + sq * 8];
    const unsigned short* bP1 = &CT[(size_t)(nBase + 64 + srow) * 512 + sq * 8];

    s16x8 a0v = *(const s16x8*)aP0;
    s16x8 a1v = *(const s16x8*)aP1;
    s16x8 b0v = *(const s16x8*)bP0;
    s16x8 b1v = *(const s16x8*)bP1;

    unsigned short* wA0 = &As[srow * 40 + sq * 8];
    unsigned short* wA1 = &As[(64 + srow) * 40 + sq * 8];
    unsigned short* wB0 = &Bs[srow * 40 + sq * 8];
    unsigned short* wB1 = &Bs[(64 + srow) * 40 + sq * 8];

    #pragma unroll
    for (int ks = 0; ks < 16; ++ks) {
        *(s16x8*)wA0 = a0v;
        *(s16x8*)wA1 = a1v;
        *(s16x8*)wB0 = b0v;
        *(s16x8*)wB1 = b1v;
        __syncthreads();
        if (ks < 15) {
            const int k0 = (ks + 1) * 32;
            a0v = *(const s16x8*)(aP0 + k0);
            a1v = *(const s16x8*)(aP1 + k0);
            b0v = *(const s16x8*)(bP0 + k0);
            b1v = *(const s16x8*)(bP1 + k0);
        }
        s16x8 af[4], bf[4];
        #pragma unroll
        for (int f = 0; f < 4; ++f) {
            af[f] = *(const s16x8*)&As[(wrow + f * 16 + (lane & 15)) * 40 + (lane >> 4) * 8];
            bf[f] = *(const s16x8*)&Bs[(wcol + f * 16 + (lane & 15)) * 40 + (lane >> 4) * 8];
        }
        #pragma unroll
        for (int fr = 0; fr < 4; ++fr)
            #pragma unroll
            for (int fc = 0; fc < 4; ++fc)
                acc[fr][fc] = __builtin_amdgcn_mfma_f32_16x16x32_bf16(
                    af[fr], bf[fc], acc[fr][fc], 0, 0, 0);
        __syncthreads();
    }

    #pragma unroll
    for (int fr = 0; fr < 4; ++fr)
    #pragma unroll
    for (int fc = 0; fc < 4; ++fc) {
        f32x4 a = acc[fr][fc];
        const int gR0 = mBase + wrow + fr * 16 + ((lane >> 4) * 4);
        const int n   = nBase + wcol + fc * 16 + (lane & 15);
        const int bb  = n >> 13, l = n & 8191;
        #pragma unroll
        for (int p = 0; p < 2; ++p) {
            float hv = a[2 * p], gv = a[2 * p + 1];
            const int ch = (gR0 >> 1) + p;
            if (ch == 0)      gv = -1000.f;
            else if (ch == 1) gv =  1000.f;
            float e  = __expf(-fabsf(gv));
            float l1 = __logf(1.f + e);                 // log1p(exp(-|g|))
            float la = fminf(-gv, 0.f) - l1;            // logsig(-g) <= 0
            float ls = fminf(gv, 0.f) - l1;             // logsig(g)
            float zb = ls + __logf(fmaxf(fabsf(hv), 1e-6f));
            float enc = (hv < 0.f) ? fabsf(la) : -fabsf(la);
            size_t off = ((size_t)bb * CH_ + ch) * L_ + l;
            ZB[off] = zb;
            LA[off] = enc;
        }
    }
}

// ---------------------------------------------------------------------------
// Kernel 3b: recompute h[b][1][:] in full f32, rewrite ch1's (la, zb).
// R12 RESTRUCTURE: scheduling fixes (x8 unroll, keep-alive, sched_barrier)
// all failed — 1 thread/output = 2 waves/CU is structurally latency-bound.
// Now: d-sum SPLIT across 8 segment-threads (each 64 ascending d, cv
// expression identical), partials combined left-to-right.  512 thr/block,
// 512 blocks -> 16 waves/CU; TLP hides latency.  NOTE: changes f32 sum
// grouping — one-time ~17% risk of a ch1 0.5-ULP quantization flip (np ref
// uses BLAS order anyway); if absmax jumps to ~0.5+, revert to r10 fixch1.
// ---------------------------------------------------------------------------
__global__ __launch_bounds__(512)
void fixch1_kernel(const float* __restrict__ x, const float* __restrict__ cw,
                   const float* __restrict__ h_w,
                   float* __restrict__ ZB, float* __restrict__ LA) {
    __shared__ float wc[512][5];
    __shared__ float w1n[512];
    __shared__ float red[8];
    __shared__ float sP[8][64];
    const int b  = blockIdx.y;
    const int t  = threadIdx.x;
    const int li = t & 63;            // l within block
    const int sg = t >> 6;            // segment 0..7 (one wave each)
    const int l  = blockIdx.x * 64 + li;
    const int lane = t & 63;
    {   // conv weight normalization: one d-row per thread
        int d = t;
        float a0 = cw[d * 5 + 0], a1 = cw[d * 5 + 1], a2 = cw[d * 5 + 2],
              a3 = cw[d * 5 + 3], a4 = cw[d * 5 + 4];
        float ss = a0 * a0 + a1 * a1 + a2 * a2 + a3 * a3 + a4 * a4;
        float sc = 1.f / (sqrtf(ss) + 1e-4f * sqrtf(5.f));
        wc[d][0] = a0 * sc; wc[d][1] = a1 * sc; wc[d][2] = a2 * sc;
        wc[d][3] = a3 * sc; wc[d][4] = a4 * sc;
    }
    {   // h_w row 1 normalization: one element per thread
        float v = h_w[512 + t];
        float ss = v * v;
        #pragma unroll
        for (int off = 32; off > 0; off >>= 1) ss += __shfl_down(ss, off, 64);
        if (lane == 0) red[sg] = ss;
        __syncthreads();
        float tot = ((red[0] + red[1]) + (red[2] + red[3]))
                  + ((red[4] + red[5]) + (red[6] + red[7]));
        float sc = 1.f / (sqrtf(tot) + 1e-4f * sqrtf(512.f));
        w1n[t] = v * sc;
    }
    __syncthreads();
    const float* xb = x + (size_t)b * D_ * L_;
    const bool lo2 = (l >= 2), lo1 = (l >= 1);
    const bool hi1 = (l + 1 < L_), hi2 = (l + 2 < L_);
    float p = 0.f;
    const int dBeg = sg * 64;
    #pragma unroll 4
    for (int i = 0; i < 64; ++i) {
        const int d = dBeg + i;
        const float* xr = xb + (size_t)d * L_;
        float x0 = lo2 ? xr[l - 2] : 0.f;
        float x1 = lo1 ? xr[l - 1] : 0.f;
        float x2 = xr[l];
        float x3 = hi1 ? xr[l + 1] : 0.f;
        float x4 = hi2 ? xr[l + 2] : 0.f;
        float cv = wc[d][0] * x0 + wc[d][1] * x1 + wc[d][2] * x2
                 + wc[d][3] * x3 + wc[d][4] * x4;
        p += w1n[d] * cv;
    }
    sP[sg][li] = p;
    __syncthreads();
    if (sg == 0) {
        float acc = sP[0][li];
        #pragma unroll
        for (int s = 1; s < 8; ++s) acc += sP[s][li];
        size_t off = ((size_t)b * CH_ + 1) * L_ + l;
        LA[off] = (acc < 0.f) ? 1000.f : -1000.f;    // la=-1000, sign packed
        ZB[off] = logf(fmaxf(fabsf(acc), 1e-6f));    // logsig(1000)=0
    }
}

// ---------------------------------------------------------------------------
// Kernel 4: log-space scan from precomputed (la_enc, zb).
// ---------------------------------------------------------------------------
struct LV { float re, sg; };

__device__ __forceinline__ LV lcomb(LV a, LV b) {
    float m  = fmaxf(a.re, b.re);
    float ms = (m > -3.0e38f) ? m : 0.f;
    float s  = a.sg * __expf(a.re - ms) + b.sg * __expf(b.re - ms);
    LV r;
    r.re = ms + __logf(fabsf(s));
    r.sg = (s < 0.f) ? -1.f : 1.f;
    return r;
}

__global__ __launch_bounds__(256)
void logscan_kernel(const float* __restrict__ LA, float* __restrict__ ZO) {
    __shared__ float wA[4];
    __shared__ float wRe[4], wSg[4];
    const int row = blockIdx.x;
    const int t = threadIdx.x;
    const int lane = t & 63, wid = t >> 6;
    const float* ep = LA + (size_t)row * L_;
    float* zp = ZO + (size_t)row * L_;

    float As[32];
    unsigned sgb = 0;
    float run = 0.f;
    #pragma unroll
    for (int i = 0; i < 8; ++i) {
        float4 e4 = *(const float4*)&ep[t * 32 + i * 4];
        float ev0 = e4.x, ev1 = e4.y, ev2 = e4.z, ev3 = e4.w;
        if (!(__float_as_uint(ev0) >> 31)) sgb |= (1u << (i * 4 + 0));
        if (!(__float_as_uint(ev1) >> 31)) sgb |= (1u << (i * 4 + 1));
        if (!(__float_as_uint(ev2) >> 31)) sgb |= (1u << (i * 4 + 2));
        if (!(__float_as_uint(ev3) >> 31)) sgb |= (1u << (i * 4 + 3));
        run -= fabsf(ev0); As[i * 4 + 0] = run;
        run -= fabsf(ev1); As[i * 4 + 1] = run;
        run -= fabsf(ev2); As[i * 4 + 2] = run;
        run -= fabsf(ev3); As[i * 4 + 3] = run;
    }
    float wsc = run;
    #pragma unroll
    for (int off = 1; off < 64; off <<= 1) {
        float u = __shfl_up(wsc, off, 64);
        if (lane >= off) wsc += u;
    }
    if (lane == 63) wA[wid] = wsc;
    __syncthreads();
    float pre = wsc - run;
    for (int j = 0; j < wid; ++j) pre += wA[j];
    #pragma unroll
    for (int i = 0; i < 32; ++i) As[i] += pre;

    float zz[32];
    LV tot = { -INFINITY, 1.f };
    #pragma unroll
    for (int i = 0; i < 8; ++i) {
        float4 z4 = *(const float4*)&zp[t * 32 + i * 4];
        float zv0 = z4.x, zv1 = z4.y, zv2 = z4.z, zv3 = z4.w;
        #pragma unroll
        for (int j = 0; j < 4; ++j) {
            int k = i * 4 + j;
            float zvj = (j == 0) ? zv0 : (j == 1) ? zv1 : (j == 2) ? zv2 : zv3;
            zz[k] = zvj - As[k];
            LV zi = { zz[k], ((sgb >> k) & 1) ? -1.f : 1.f };
            tot = lcomb(tot, zi);
        }
    }
    LV sc = tot;
    #pragma unroll
    for (int off = 1; off < 64; off <<= 1) {
        float ure = __shfl_up(sc.re, off, 64);
        float usg = __shfl_up(sc.sg, off, 64);
        if (lane >= off) { LV u = { ure, usg }; sc = lcomb(u, sc); }
    }
    if (lane == 63) { wRe[wid] = sc.re; wSg[wid] = sc.sg; }
    __syncthreads();
    float pr = __shfl_up(sc.re, 1, 64);
    float ps = __shfl_up(sc.sg, 1, 64);
    LV lex = { -INFINITY, 1.f };
    if (lane != 0) { lex.re = pr; lex.sg = ps; }
    LV wpre = { -INFINITY, 1.f };
    for (int j = 0; j < wid; ++j) { LV u = { wRe[j], wSg[j] }; wpre = lcomb(wpre, u); }
    LV pref = lcomb(wpre, lex);

    LV run2 = pref;
    #pragma unroll
    for (int i = 0; i < 8; ++i) {
        float4 o4;
        #pragma unroll
        for (int j = 0; j < 4; ++j) {
            int k = i * 4 + j;
            LV zi = { zz[k], ((sgb >> k) & 1) ? -1.f : 1.f };
            run2 = lcomb(run2, zi);
            float ov = run2.sg * __expf(As[k] + run2.re);
            if (j == 0) o4.x = ov; else if (j == 1) o4.y = ov;
            else if (j == 2) o4.z = ov; else o4.w = ov;
        }
        *(float4*)&zp[t * 32 + i * 4] = o4;
    }
}

// ---------------------------------------------------------------------------
extern "C" void kernel_launch(void* const* d_in, const int* in_sizes, int n_in,
                              void* d_out, int out_size, void* d_ws, size_t ws_size,
                              hipStream_t stream) {
    const float* x      = (const float*)d_in[0];
    const float* conv_w = (const float*)d_in[1];
    const float* h_w    = (const float*)d_in[2];
    const float* g_w    = (const float*)d_in[3];
    float* out = (float*)d_out;
    char* ws = (char*)d_ws;

    // ws layout (97 MB): CT bf16 [32768][512] = 32MB | Wn bf16 1MB | LA f32 64MB
    unsigned short* CT  = (unsigned short*)ws;
    unsigned short* Wn  = (unsigned short*)(ws + (size_t)32 * 1024 * 1024);
    float*          la  = (float*)(ws + (size_t)33 * 1024 * 1024);
    unsigned short* C   = (unsigned short*)d_out;

    prep_kernel<<<512, 256, 0, stream>>>(h_w, g_w, Wn);
    conv_kernel<<<B_ * D_, 256, 0, stream>>>(x, conv_w, C);
    transpose_kernel<<<dim3(128, 8, 4), 256, 0, stream>>>(C, CT);
    gemm_kernel<<<2048, 256, 0, stream>>>(Wn, CT, out, la);
    fixch1_kernel<<<dim3(L_ / 64, B_), 512, 0, stream>>>(x, conv_w, h_w, out, la);
    logscan_kernel<<<B_ * CH_, 256, 0, stream>>>(la, out);
}